// Round 3
// baseline (360.754 us; speedup 1.0000x reference)
//
#include <hip/hip_runtime.h>
#include <math.h>

#define MAXDEG 20
#define NM 21               // m = 0..20
#define RANK 256
#define PPB 12              // points per block
#define NSLOT (2*PPB)       // 24 (point,dir) slots
#define NROW 231            // packed (l,m) rows: base(m)=21m-m(m-1)/2, row=base+(l-m)

// Transposed LDS layout: tables are [row][point] so one lane's gather index
// yields 12 CONTIGUOUS words (48B, 16B-aligned) -> 3x ds_read_b128 per table.
//   s_tA/s_tB : Pbar_{l,m} (sqrt2 + Condon-Shortley folded), sides A/B
//   s_tgA/s_tgB : rows 0..20 = cos(m phi), rows 21..41 = sin(m phi)
//   Y_{l,+m} = tab[row(l,m)][p] * tg[m][p];  Y_{l,-m} = tab[row][p] * tg[21+m][p]

__device__ __forceinline__ void remap2(int k, int& pi, int& ti) {
  // flax index k = l*(l+1)+m  ->  (Legendre row, trig row)
  int l = (int)sqrtf((float)k);
  if (l*l > k) --l;
  if ((l+1)*(l+1) <= k) ++l;
  int m = k - l*(l+1);
  int am = m < 0 ? -m : m;
  pi = 21*am - (am*(am-1))/2 + (l - am);
  ti = (m == 0) ? 0 : (m > 0 ? am : 21 + am);
}

__global__ __launch_bounds__(256, 5)
void sh_fused(const float* __restrict__ coords,
              const int* __restrict__ rand_i,
              const int* __restrict__ rand_j,
              float* __restrict__ out, int N) {
  __shared__ float2 s_ab[NROW];             // recurrence coeffs (a,b) per tri(l,m)
  __shared__ float  s_c1[NM];               // sqrt(2m+3)
  __shared__ float  s_hx[NSLOT];            // x = cos(inclination) per slot
  __shared__ float  s_pm[NM * NSLOT];       // Pmm seeds, [m][slot]
  __shared__ __align__(16) float s_tgA[42 * PPB];   // trig [row][point], side A
  __shared__ __align__(16) float s_tgB[42 * PPB];   // side B
  __shared__ __align__(16) float s_tA[NROW * PPB];  // Legendre [row][point], side A
  __shared__ __align__(16) float s_tB[NROW * PPB];  // side B

  const int t  = threadIdx.x;
  const int n0 = blockIdx.x * PPB;

  // ---- remap gather indices (once, registers) ----
  int rip, rit, rjp, rjt;
  remap2(rand_i[t], rip, rit);
  remap2(rand_j[t], rjp, rjt);

  // ---- phase 0a: coefficient tables. tri index t -> (l,m) ----
  if (t < NROW) {
    int l = (int)((sqrtf(8.0f*(float)t + 1.0f) - 1.0f) * 0.5f);
    if (l*(l+1)/2 > t) --l;
    if ((l+1)*(l+2)/2 <= t) ++l;
    int m = t - l*(l+1)/2;
    float a = 0.f, b = 0.f;
    if (l >= m + 2) {
      float l2 = (float)(l*l), m2 = (float)(m*m);
      float inv = 1.0f / (l2 - m2);
      a = sqrtf((4.f*l2 - 1.f) * inv);
      b = sqrtf((2.f*(float)l + 1.f) * ((float)((l-1)*(l-1)) - m2)
                / (2.f*(float)l - 3.f) * inv);
    }
    s_ab[t] = make_float2(a, b);
  }
  if (t < NM) s_c1[t] = sqrtf(2.f*(float)t + 3.f);

  // ---- phase 0b: per-(point,dir) header (trig rotation + Pmm seeds) ----
  if (t < NSLOT) {
    int p = t >> 1, d = t & 1;
    int n = n0 + p; if (n >= N) n = N - 1;
    const float* c = coords + (size_t)n * 6 + d * 3;
    float cx = c[0], cy = c[1], cz = c[2];
    float r2 = cx*cx + cy*cy + cz*cz;
    float x = cz * rsqrtf(r2);                 // cos(inclination)
    x = fminf(1.f, fmaxf(-1.f, x));
    float s = sqrtf(fmaxf(0.f, 1.f - x*x));    // sin(inclination) >= 0
    float rho2 = cx*cx + cy*cy;
    float cphi, sphi;
    if (rho2 > 0.f) { float ir = rsqrtf(rho2); cphi = cx*ir; sphi = cy*ir; }
    else            { cphi = 1.f; sphi = 0.f; }   // atan2(0,0)=0 convention
    s_hx[t] = x;
    float* tg = d ? s_tgB : s_tgA;
    tg[0*PPB + p]  = 1.f;                      // cos(0*phi)
    tg[21*PPB + p] = 0.f;                      // sin(0*phi), never gathered
    float pmm = 0.28209479177387814f;          // sqrt(1/(4*pi)) = Pbar_00
    s_pm[0*NSLOT + t] = pmm;
    float cm = 1.f, sm = 0.f;
    #pragma unroll
    for (int m = 1; m <= MAXDEG; ++m) {
      float cn = cm*cphi - sm*sphi;            // incremental rotation
      float sn = sm*cphi + cm*sphi;
      cm = cn; sm = sn;
      // (2m+1)/(2m) is a compile-time literal after unroll -> sqrtf folds
      float df = -sqrtf((2.f*(float)m + 1.f) / (2.f*(float)m));  // CS phase
      if (m == 1) df *= 1.41421356237309515f;  // fold sqrt(2) for all m>=1
      pmm = df * s * pmm;
      tg[m*PPB + p]      = cm;
      tg[(21+m)*PPB + p] = sm;
      s_pm[m*NSLOT + t]  = pmm;
    }
  }
  __syncthreads();

  // ---- phase 1: fill transposed Legendre tables ----
  for (int task = t; task < NM * NSLOT; task += 256) {
    int m  = task / NSLOT;          // major = m (sorted -> low trip-count divergence)
    int pd = task - m * NSLOT;
    int d  = pd & 1, p = pd >> 1;
    float x  = s_hx[pd];
    float p1 = s_pm[m*NSLOT + pd];
    float* tT = (d ? s_tB : s_tA) + (21*m - (m*(m-1))/2)*PPB + p;
    tT[0] = p1;                                // l = m
    if (m < MAXDEG) {
      float p2 = p1;
      float pc = s_c1[m] * x * p1;             // l = m+1
      tT[PPB] = pc;
      int ti = (m+2)*(m+3)/2 + m;              // tri(m+2, m)
      for (int l = m+2; l <= MAXDEG; ++l) {
        float2 ab = s_ab[ti];
        float pn = ab.x * (x * pc) - ab.y * p2;
        p2 = pc; pc = pn;
        tT[(l-m)*PPB] = pn;
        ti += l + 1;
      }
    }
  }
  __syncthreads();

  // ---- phase 2: vectorized gathers (3x b128 per table), coalesced store ----
  const float* pA  = s_tA  + rip * PPB;
  const float* pTa = s_tgA + rit * PPB;
  const float* pB  = s_tB  + rjp * PPB;
  const float* pTb = s_tgB + rjt * PPB;
  #pragma unroll
  for (int k = 0; k < PPB/4; ++k) {
    float4 a  = *(const float4*)(pA  + 4*k);
    float4 ta = *(const float4*)(pTa + 4*k);
    float4 b  = *(const float4*)(pB  + 4*k);
    float4 tb = *(const float4*)(pTb + 4*k);
    #pragma unroll
    for (int j = 0; j < 4; ++j) {
      int n = n0 + 4*k + j;
      if (n < N) {
        float av = (&a.x)[j] * (&ta.x)[j];
        float bv = (&b.x)[j] * (&tb.x)[j];
        out[(size_t)n * RANK + t] = av * bv;
      }
    }
  }
}

extern "C" void kernel_launch(void* const* d_in, const int* in_sizes, int n_in,
                              void* d_out, int out_size, void* d_ws, size_t ws_size,
                              hipStream_t stream) {
  const float* coords = (const float*)d_in[0];
  const int*   rand_i = (const int*)d_in[1];
  const int*   rand_j = (const int*)d_in[2];
  float*       out    = (float*)d_out;
  const int N = in_sizes[0] / 6;
  const int grid = (N + PPB - 1) / PPB;
  sh_fused<<<grid, 256, 0, stream>>>(coords, rand_i, rand_j, out, N);
}